// Round 2
// baseline (181.001 us; speedup 1.0000x reference)
//
#include <hip/hip_runtime.h>

// out[p][f] = sum_s x[p][s] * K[s][f];  P = 393,216, K 64x64 fp32.
//
// R7: R6 falsified the latency theory -- removing LDS/barriers/conflicts and
// adding prefetch changed nothing (59.4 -> 60.8us). All pipes idle, HBM 31%.
// Yet m13's float4 copy does the SAME 1:1 read:write mix at 6.29 TB/s, and
// the harness fill hits 6.75 TB/s at 9% occupancy -> concurrency is not the
// limit. Remaining suspect: cache-hierarchy interference -- our write stream
// allocates/dirties L2+L3, evicting the L3-resident input (FETCH=50MB of a
// 100MB input = eviction churn every iteration), and the two streams contend
// in the MALL. Fix: NON-TEMPORAL stores (nt flag, the fill's streaming path)
// so writes stop allocating in L2/L3; reads keep L3 residency. Also
// interleave stores per-ft chain for earlier store issue.
// Numerics unchanged: 3-term bf16 hi/lo split (absmax 0.03125).
// Prediction: dur 60.8 -> 30-40us if theory holds (FETCH drops, WRITE same,
// hbm_gbps 2.5 -> 4+ TB/s); if null (58-63us), cache theory falsified ->
// next round runs a control (pure-copy) kernel to find the real ceiling.

#define THREADS 256
#define WPB     4          // waves per block
#define TPW     3          // tiles per wave (24576 wave-tiles / 8192 waves)

typedef __attribute__((ext_vector_type(8))) short bf16x8;
typedef __attribute__((ext_vector_type(4))) float f32x4;

static __device__ __forceinline__ unsigned short bf16_rne(float f) {
    unsigned int u = __float_as_uint(f);
    u += 0x7fffu + ((u >> 16) & 1u);
    return (unsigned short)(u >> 16);
}
static __device__ __forceinline__ float bf16f(unsigned short h) {
    return __uint_as_float((unsigned int)h << 16);
}

__global__ __launch_bounds__(THREADS)
void dct_kernel(const float* __restrict__ x,
                const float* __restrict__ Kmat,
                float* __restrict__ out,
                int ntiles) {
    __shared__ short bhi[8 * 64 * 8];   // 8 KB  [combo][lane][j]
    __shared__ short blo[8 * 64 * 8];   // 8 KB

    const int tid  = threadIdx.x;
    const int lane = tid & 63;
    const int wv   = tid >> 6;          // 0..3
    const int l15  = lane & 15;
    const int quad = lane >> 4;         // 0..3

    const int totw = (int)gridDim.x * WPB;              // total waves
    const long long wt0 = (long long)blockIdx.x * WPB + wv;
    const float* src = x + (wt0 * 16 + l15) * 64 + quad * 8;
    float* dst = out + wt0 * 1024;
    const long long SSTEP = (long long)totw * 1024;     // floats between a wave's tiles

    // ---- issue tile-0 loads FIRST: HBM latency hides under K build ----
    float4 c0, c1, c2, c3;
    if (wt0 < ntiles) {
        c0 = *(const float4*)(src);
        c1 = *(const float4*)(src + 4);
        c2 = *(const float4*)(src + 32);
        c3 = *(const float4*)(src + 36);
    }

    // ---- build K bf16 hi/lo B-frags once; wave wv builds combos 2wv,2wv+1 --
    // combo = kc*4 + ft ; lane holds B[k = kc*32+quad*8+j][n = ft*16+l15]
#pragma unroll
    for (int cc = 0; cc < 2; ++cc) {
        const int combo = wv * 2 + cc;
        const int kc = combo >> 2, ft = combo & 3;
        short hh[8], ll[8];
#pragma unroll
        for (int j = 0; j < 8; ++j) {
            float v = Kmat[(kc * 32 + quad * 8 + j) * 64 + ft * 16 + l15];
            unsigned short h = bf16_rne(v);
            hh[j] = (short)h;
            ll[j] = (short)bf16_rne(v - bf16f(h));
        }
        *(bf16x8*)&bhi[(combo * 64 + lane) * 8] = *(bf16x8*)hh;  // lane-linear 16B
        *(bf16x8*)&blo[(combo * 64 + lane) * 8] = *(bf16x8*)ll;
    }
    __syncthreads();

    // ---- hoist all 16 B-frags to registers (64 VGPR); LDS done after this --
    bf16x8 Bh[8], Bl[8];
#pragma unroll
    for (int c = 0; c < 8; ++c) {
        Bh[c] = *(const bf16x8*)&bhi[(c * 64 + lane) * 8];
        Bl[c] = *(const bf16x8*)&blo[(c * 64 + lane) * 8];
    }

    // ---- streaming main loop: prefetch next tile, compute current ----
#pragma unroll
    for (int s = 0; s < TPW; ++s) {
        if (wt0 + (long long)s * totw >= ntiles) break;

        float4 n0, n1, n2, n3;
        const bool more = (s + 1 < TPW) && (wt0 + (long long)(s + 1) * totw < ntiles);
        if (more) {
            const float* ns = src + (long long)(s + 1) * SSTEP;
            n0 = *(const float4*)(ns);
            n1 = *(const float4*)(ns + 4);
            n2 = *(const float4*)(ns + 32);
            n3 = *(const float4*)(ns + 36);
        }

        // convert both kc A-fragments up front
        bf16x8 Ahi[2], Alo[2];
#pragma unroll
        for (int kc = 0; kc < 2; ++kc) {
            float av[8];
            *(float4*)&av[0] = kc ? c2 : c0;
            *(float4*)&av[4] = kc ? c3 : c1;
            short ah[8], al[8];
#pragma unroll
            for (int j = 0; j < 8; ++j) {
                unsigned short h = bf16_rne(av[j]);
                ah[j] = (short)h;
                al[j] = (short)bf16_rne(av[j] - bf16f(h));
            }
            Ahi[kc] = *(bf16x8*)ah;
            Alo[kc] = *(bf16x8*)al;
        }

        // per-ft: 6-MFMA chain then 4 nt stores (earlier store issue,
        // stores of ft overlap MFMAs of ft+1)
        float* ob = dst + (long long)s * SSTEP;
#pragma unroll
        for (int ft = 0; ft < 4; ++ft) {
            f32x4 a = (f32x4){0.f, 0.f, 0.f, 0.f};
#pragma unroll
            for (int kc = 0; kc < 2; ++kc) {
                const int c = kc * 4 + ft;
                a = __builtin_amdgcn_mfma_f32_16x16x32_bf16(Ahi[kc], Bh[c], a, 0, 0, 0);
                a = __builtin_amdgcn_mfma_f32_16x16x32_bf16(Alo[kc], Bh[c], a, 0, 0, 0);
                a = __builtin_amdgcn_mfma_f32_16x16x32_bf16(Ahi[kc], Bl[c], a, 0, 0, 0);
            }
            // C/D layout: col = l15, row = quad*4 + r; nt -> no L2/L3 allocate
#pragma unroll
            for (int r = 0; r < 4; ++r)
                __builtin_nontemporal_store(a[r], &ob[(quad * 4 + r) * 64 + ft * 16 + l15]);
        }

        if (more) { c0 = n0; c1 = n1; c2 = n2; c3 = n3; }
    }
}

extern "C" void kernel_launch(void* const* d_in, const int* in_sizes, int n_in,
                              void* d_out, int out_size, void* d_ws, size_t ws_size,
                              hipStream_t stream) {
    const float* x = (const float*)d_in[0];   // (8,3,1024,1024) fp32
    const float* K = (const float*)d_in[1];   // (64,64) fp32
    float* out = (float*)d_out;

    const int total = in_sizes[0];            // 25,165,824 floats
    const int num_patches = total / 64;       // 393,216
    const int wave_tiles  = num_patches / 16; // 24,576
    const int blocks = (wave_tiles + WPB * TPW - 1) / (WPB * TPW);  // 2048

    dct_kernel<<<blocks, THREADS, 0, stream>>>(x, K, out, wave_tiles);
}

// Round 4
// 174.577 us; speedup vs baseline: 1.0368x; 1.0368x over previous
//
#include <hip/hip_runtime.h>

// out[p][f] = sum_s x[p][s] * K[s][f];  P = 393,216, K 64x64 fp32.
//
// R8b (R8 retry; only fix: __builtin_nontemporal_store needs a clang
// ext_vector pointer, not HIP's float4 struct).
// Ledger -- R6 killed the latency theory, R7's nt-on-scattered-dwords
// regressed via write amplification (WRITE 98->121MB: partial 64B lines hit
// HBM uncombined). The one stream never changed across R5/R6/R7 (all ~60us,
// 2.5 TB/s, pipes idle) is the STORE pattern: 16x global_store_dword per
// tile, 4 scattered 64B segments each. Every kernel that reaches 6.3-6.8
// TB/s (m13 copy, harness fill) stores lane-contiguous dwordx4. Also
// FETCH=50MB (half input L3-resident despite 402MB fill between runs) =>
// the fill is non-allocating; OUR allocating writes are what evict the
// input. Fix both: transpose acc through per-wave-private LDS (barrier-free,
// 2-way bank aliasing = free per m136) -> 4x contiguous nt dwordx4 stores
// per tile. Full-granule nt => no amplification + input stays L3-resident.
// Numerics unchanged (3-term bf16 hi/lo, absmax 0.03125).
// Prediction: WRITE back to ~98MB, FETCH 49 -> <=25MB, dur 60 -> 30-40us.
// If null: stores exonerated; next round = stripped-compute control probe.

#define THREADS 256
#define WPB     4          // waves per block
#define TPW     3          // tiles per wave (24576 wave-tiles / 8192 waves)
#define OROW    68         // ostage row stride (floats): +4 pad -> 2-way max

typedef __attribute__((ext_vector_type(8))) short bf16x8;
typedef __attribute__((ext_vector_type(4))) float f32x4;

static __device__ __forceinline__ unsigned short bf16_rne(float f) {
    unsigned int u = __float_as_uint(f);
    u += 0x7fffu + ((u >> 16) & 1u);
    return (unsigned short)(u >> 16);
}
static __device__ __forceinline__ float bf16f(unsigned short h) {
    return __uint_as_float((unsigned int)h << 16);
}

__global__ __launch_bounds__(THREADS)
void dct_kernel(const float* __restrict__ x,
                const float* __restrict__ Kmat,
                float* __restrict__ out,
                int ntiles) {
    __shared__ short bhi[8 * 64 * 8];                    //  8 KB [combo][lane][j]
    __shared__ short blo[8 * 64 * 8];                    //  8 KB
    __shared__ __align__(16) float ost[WPB][16][OROW];   // 17 KB wave-private

    const int tid  = threadIdx.x;
    const int lane = tid & 63;
    const int wv   = tid >> 6;          // 0..3
    const int l15  = lane & 15;
    const int quad = lane >> 4;         // 0..3

    const int totw = (int)gridDim.x * WPB;              // total waves
    const long long wt0 = (long long)blockIdx.x * WPB + wv;
    const float* src = x + (wt0 * 16 + l15) * 64 + quad * 8;
    float* dst = out + wt0 * 1024;
    const long long SSTEP = (long long)totw * 1024;     // floats between a wave's tiles

    // ---- issue tile-0 loads FIRST: HBM latency hides under K build ----
    float4 c0, c1, c2, c3;
    if (wt0 < ntiles) {
        c0 = *(const float4*)(src);
        c1 = *(const float4*)(src + 4);
        c2 = *(const float4*)(src + 32);
        c3 = *(const float4*)(src + 36);
    }

    // ---- build K bf16 hi/lo B-frags once; wave wv builds combos 2wv,2wv+1 --
    // combo = kc*4 + ft ; lane holds B[k = kc*32+quad*8+j][n = ft*16+l15]
#pragma unroll
    for (int cc = 0; cc < 2; ++cc) {
        const int combo = wv * 2 + cc;
        const int kc = combo >> 2, ft = combo & 3;
        short hh[8], ll[8];
#pragma unroll
        for (int j = 0; j < 8; ++j) {
            float v = Kmat[(kc * 32 + quad * 8 + j) * 64 + ft * 16 + l15];
            unsigned short h = bf16_rne(v);
            hh[j] = (short)h;
            ll[j] = (short)bf16_rne(v - bf16f(h));
        }
        *(bf16x8*)&bhi[(combo * 64 + lane) * 8] = *(bf16x8*)hh;  // lane-linear 16B
        *(bf16x8*)&blo[(combo * 64 + lane) * 8] = *(bf16x8*)ll;
    }
    __syncthreads();

    // ---- hoist all 16 B-frags to registers (64 VGPR); LDS K done ----
    bf16x8 Bh[8], Bl[8];
#pragma unroll
    for (int c = 0; c < 8; ++c) {
        Bh[c] = *(const bf16x8*)&bhi[(c * 64 + lane) * 8];
        Bl[c] = *(const bf16x8*)&blo[(c * 64 + lane) * 8];
    }

    // ---- streaming main loop: prefetch next tile, compute current ----
#pragma unroll
    for (int s = 0; s < TPW; ++s) {
        if (wt0 + (long long)s * totw >= ntiles) break;

        float4 n0, n1, n2, n3;
        const bool more = (s + 1 < TPW) && (wt0 + (long long)(s + 1) * totw < ntiles);
        if (more) {
            const float* ns = src + (long long)(s + 1) * SSTEP;
            n0 = *(const float4*)(ns);
            n1 = *(const float4*)(ns + 4);
            n2 = *(const float4*)(ns + 32);
            n3 = *(const float4*)(ns + 36);
        }

        // convert both kc A-fragments
        bf16x8 Ahi[2], Alo[2];
#pragma unroll
        for (int kc = 0; kc < 2; ++kc) {
            float av[8];
            *(float4*)&av[0] = kc ? c2 : c0;
            *(float4*)&av[4] = kc ? c3 : c1;
            short ah[8], al[8];
#pragma unroll
            for (int j = 0; j < 8; ++j) {
                unsigned short h = bf16_rne(av[j]);
                ah[j] = (short)h;
                al[j] = (short)bf16_rne(av[j] - bf16f(h));
            }
            Ahi[kc] = *(bf16x8*)ah;
            Alo[kc] = *(bf16x8*)al;
        }

        f32x4 acc[4];
#pragma unroll
        for (int t = 0; t < 4; ++t) acc[t] = (f32x4){0.f, 0.f, 0.f, 0.f};
#pragma unroll
        for (int kc = 0; kc < 2; ++kc)
#pragma unroll
            for (int ft = 0; ft < 4; ++ft) {
                const int c = kc * 4 + ft;
                acc[ft] = __builtin_amdgcn_mfma_f32_16x16x32_bf16(Ahi[kc], Bh[c], acc[ft], 0, 0, 0);
                acc[ft] = __builtin_amdgcn_mfma_f32_16x16x32_bf16(Alo[kc], Bh[c], acc[ft], 0, 0, 0);
                acc[ft] = __builtin_amdgcn_mfma_f32_16x16x32_bf16(Ahi[kc], Bl[c], acc[ft], 0, 0, 0);
            }

        // ---- epilogue: wave-private LDS transpose -> contiguous nt x4 ----
        // C/D frag: lane (quad,l15) holds row quad*4+r, col ft*16+l15.
        // write: bank = (16q + 4r + 16ft + l15)&31 -> exactly 2-way (free).
#pragma unroll
        for (int ft = 0; ft < 4; ++ft)
#pragma unroll
            for (int r = 0; r < 4; ++r)
                ost[wv][quad * 4 + r][ft * 16 + l15] = acc[ft][r];
        // same-wave readback (compiler inserts lgkmcnt; no barrier needed):
        // lane j stores floats [i*256 + j*4, +4) of the 4KB tile -> 1KB
        // contiguous per instr, full 64B granules -> nt safe (no amplif.)
        float* ob = dst + (long long)s * SSTEP;
#pragma unroll
        for (int i = 0; i < 4; ++i) {
            f32x4 v = *(const f32x4*)&ost[wv][i * 4 + quad][l15 * 4];
            __builtin_nontemporal_store(v, (f32x4*)(ob + i * 256 + lane * 4));
        }

        if (more) { c0 = n0; c1 = n1; c2 = n2; c3 = n3; }
    }
}

extern "C" void kernel_launch(void* const* d_in, const int* in_sizes, int n_in,
                              void* d_out, int out_size, void* d_ws, size_t ws_size,
                              hipStream_t stream) {
    const float* x = (const float*)d_in[0];   // (8,3,1024,1024) fp32
    const float* K = (const float*)d_in[1];   // (64,64) fp32
    float* out = (float*)d_out;

    const int total = in_sizes[0];            // 25,165,824 floats
    const int num_patches = total / 64;       // 393,216
    const int wave_tiles  = num_patches / 16; // 24,576
    const int blocks = (wave_tiles + WPB * TPW - 1) / (WPB * TPW);  // 2048

    dct_kernel<<<blocks, THREADS, 0, stream>>>(x, K, out, wave_tiles);
}